// Round 3
// baseline (412.842 us; speedup 1.0000x reference)
//
#include <hip/hip_runtime.h>

// SosModel: cascade of 4 biquads over T=32768, per (batch,channel); B=16, C=64.
// Overlap-save: each wave = one (batch, 64-step chunk), WARM=96 warm-up.
// For chunk k=1 the warm-up window starts at t=-32: negative rows are fed as
// ZEROS (exact: zero input from zero state keeps state zero => k=1 chunk is
// bit-exact warm-up from t=0). For k>=2, truncation ~0.9^96*gain ~1e-3 << 2.6e-2.
// lane == channel -> one contiguous 256B row load/store per wave per step.
//
// R3 vs R2: fix OOB crash. CHUNK(64) < WARM(96) makes s0 negative for k=1;
// R2's ISSUE only clamped the high end, so priming loads read x[-32*64..]
// -> illegal address. s0 = 0 mod 8 guarantees a group is either entirely
// negative or entirely >=0, so the fix is one wave-uniform scalar branch per
// ISSUE: negative group -> zero-fill buffer (no loads).
//
// R2 theory (unchanged, now actually measurable): R1 was latency-bound
// (VALUBusy 26%, HBM 35%, 4 waves/SIMD). CHUNK 128->64 doubles TLP:
// 8192 waves, 8 blocks/CU, 8 waves/SIMD (launch_bounds(256,8), VGPR ~56 <= 64).

#define TLEN  32768
#define CCH   64
#define BATCH 16
#define NSEC  4
#define CHUNK 64
#define WARM  96         // multiple of 8; phase-1 = 12 groups = 4 x 3-rotation
#define SKEW  3          // NSEC-1 pipeline delay

#define NCHUNKS (TLEN / CHUNK)          // 512
#define NWAVES  (BATCH * NCHUNKS)       // 8192
#define BLOCK   256
#define NBLOCKS (NWAVES * 64 / BLOCK)   // 2048 -> 8 blocks/CU, 32 waves/CU

// Issue 8 row loads for group G into buffer NB.
// Negative group (only k=1 warm-up, rows -32..-1): zero-fill == exact zero
// input before t=0. High clamp: only the last chunk, and clamped rows
// provably never reach a stored output (o3 at iter i depends on inputs at
// iters <= i-3; last stored iter consumes input row <= s0+159 = TLEN-1).
#define ISSUE(NB, G) do {                                                     \
    int rb_ = s0 + 8 * (G);                                                   \
    if (rb_ < 0) {                                                            \
        NB[0] = NB[1] = NB[2] = NB[3] = 0.0f;                                 \
        NB[4] = NB[5] = NB[6] = NB[7] = 0.0f;                                 \
    } else {                                                                  \
        rb_ = (rb_ > TLEN - 8) ? (TLEN - 8) : rb_;                            \
        const float* __restrict__ p_ = xb + (size_t)rb_ * CCH;                \
        NB[0] = p_[0 * CCH]; NB[1] = p_[1 * CCH];                             \
        NB[2] = p_[2 * CCH]; NB[3] = p_[3 * CCH];                             \
        NB[4] = p_[4 * CCH]; NB[5] = p_[5 * CCH];                             \
        NB[6] = p_[6 * CCH]; NB[7] = p_[7 * CCH];                             \
    }                                                                         \
} while (0)

// One skewed-pipeline step; store predicate (SB <= j < SE) is compile-time.
#define STEP(CB, j, ps, SB, SE) do {                                          \
    const float i0 = CB[j], i1 = lat1, i2 = lat2, i3 = lat3;                  \
    const float p0 = fmaf(cb0[0], i0, fmaf(cb1[0], x1[0], cb2[0] * x2[0]));   \
    const float p1 = fmaf(cb0[1], i1, fmaf(cb1[1], x1[1], cb2[1] * x2[1]));   \
    const float p2 = fmaf(cb0[2], i2, fmaf(cb1[2], x1[2], cb2[2] * x2[2]));   \
    const float p3 = fmaf(cb0[3], i3, fmaf(cb1[3], x1[3], cb2[3] * x2[3]));   \
    const float o0 = fmaf(ca1[0], y1v[0], fmaf(ca2[0], y2v[0], p0));          \
    const float o1 = fmaf(ca1[1], y1v[1], fmaf(ca2[1], y2v[1], p1));          \
    const float o2 = fmaf(ca1[2], y1v[2], fmaf(ca2[2], y2v[2], p2));          \
    const float o3 = fmaf(ca1[3], y1v[3], fmaf(ca2[3], y2v[3], p3));          \
    x2[0] = x1[0]; x1[0] = i0;  y2v[0] = y1v[0]; y1v[0] = o0;                 \
    x2[1] = x1[1]; x1[1] = i1;  y2v[1] = y1v[1]; y1v[1] = o1;                 \
    x2[2] = x1[2]; x1[2] = i2;  y2v[2] = y1v[2]; y1v[2] = o2;                 \
    x2[3] = x1[3]; x1[3] = i3;  y2v[3] = y1v[3]; y1v[3] = o3;                 \
    lat1 = o0; lat2 = o1; lat3 = o2;                                          \
    if ((j) >= (SB) && (j) < (SE)) ps[(j) * CCH] = o3;                        \
} while (0)

// Full group: prefetch group G+2 into NB, compute 8 steps from CB,
// store rows per compile-time mask. H = group index within the store phase
// (store row for (H,j) is 8*H - 3 + j relative to py).
#define GROUP(CB, NB, G, H, SB, SE) do {                                      \
    ISSUE(NB, (G) + 2);                                                       \
    float* __restrict__ ps = py + (ptrdiff_t)(8 * (H) - 3) * CCH;             \
    STEP(CB, 0, ps, SB, SE); STEP(CB, 1, ps, SB, SE);                         \
    STEP(CB, 2, ps, SB, SE); STEP(CB, 3, ps, SB, SE);                         \
    STEP(CB, 4, ps, SB, SE); STEP(CB, 5, ps, SB, SE);                         \
    STEP(CB, 6, ps, SB, SE); STEP(CB, 7, ps, SB, SE);                         \
} while (0)

// Same, but no prefetch (used where the prefetch target is never consumed).
#define GROUP_NOPF(CB, H, SB, SE) do {                                        \
    float* __restrict__ ps = py + (ptrdiff_t)(8 * (H) - 3) * CCH;             \
    STEP(CB, 0, ps, SB, SE); STEP(CB, 1, ps, SB, SE);                         \
    STEP(CB, 2, ps, SB, SE); STEP(CB, 3, ps, SB, SE);                         \
    STEP(CB, 4, ps, SB, SE); STEP(CB, 5, ps, SB, SE);                         \
    STEP(CB, 6, ps, SB, SE); STEP(CB, 7, ps, SB, SE);                         \
} while (0)

__global__ __launch_bounds__(BLOCK, 8) void sos_kernel(const float* __restrict__ x,
                                                       const float* __restrict__ sos,
                                                       float* __restrict__ out) {
    const int lane = threadIdx.x & 63;                      // channel
    // Force wave-uniformity so all chunk/row math lands on the scalar pipe.
    const int wid  = __builtin_amdgcn_readfirstlane(
                         blockIdx.x * (BLOCK >> 6) + (threadIdx.x >> 6));
    const int b    = wid >> 9;                              // wid / NCHUNKS
    const int k    = wid & (NCHUNKS - 1);
    const int t0   = k * CHUNK;
    const int warm = k ? WARM : 0;
    const int s0   = t0 - warm;                             // -32 only when k==1

    const float* __restrict__ xb = x + (size_t)b * TLEN * CCH + lane;
    float* __restrict__ py = out + ((size_t)b * TLEN + (size_t)t0) * CCH + lane;

    // Prime the pipeline: groups 0 and 1 in flight before anything else.
    float Af[8], Bf[8], Cf[8];
    ISSUE(Af, 0);
    ISSUE(Bf, 1);

    // Coefficients (wave-uniform -> SGPRs); honor /a0 though a0==1 here.
    float cb0[NSEC], cb1[NSEC], cb2[NSEC], ca1[NSEC], ca2[NSEC];
    float x1[NSEC], x2[NSEC], y1v[NSEC], y2v[NSEC];
#pragma unroll
    for (int s = 0; s < NSEC; ++s) {
        const float inva = 1.0f / sos[s * 6 + 3];
        cb0[s] =  sos[s * 6 + 0] * inva;
        cb1[s] =  sos[s * 6 + 1] * inva;
        cb2[s] =  sos[s * 6 + 2] * inva;
        ca1[s] = -sos[s * 6 + 4] * inva;
        ca2[s] = -sos[s * 6 + 5] * inva;
        x1[s] = x2[s] = y1v[s] = y2v[s] = 0.0f;
    }
    float lat1 = 0.0f, lat2 = 0.0f, lat3 = 0.0f;   // inter-section pipeline latches

    int g = 0;
    // Phase 1 (chunks k>=1 only): 12 warm-up groups, no stores.
    if (warm) {
#pragma unroll 1
        for (int t = 0; t < 4; ++t) {
            GROUP(Af, Cf, g + 0, 0, 0, 0);
            GROUP(Bf, Af, g + 1, 0, 0, 0);
            GROUP(Cf, Bf, g + 2, 0, 0, 0);
            g += 3;
        }
    }
    // Phase 2: first store group (skew head): store j=3..7 -> rows 0..4.
    GROUP(Af, Cf, g + 0, 0, 3, 8);
    // Phase 3: 6 full-store groups -> rows 5..52, then one no-prefetch
    // full-store group -> rows 53..60 (its prefetch target is never read).
    GROUP(Bf, Af, g + 1, 1, 0, 8);
    GROUP(Cf, Bf, g + 2, 2, 0, 8);
    GROUP(Af, Cf, g + 3, 3, 0, 8);
    GROUP(Bf, Af, g + 4, 4, 0, 8);
    GROUP(Cf, Bf, g + 5, 5, 0, 8);
    GROUP(Af, Cf, g + 6, 6, 0, 8);
    GROUP_NOPF(Bf, 7, 0, 8);
    // Phase 4 (skew tail): store j=0..2 -> rows 61..63 from group g+8 (in Cf).
    {
        float* __restrict__ ps = py + (ptrdiff_t)(8 * 8 - 3) * CCH;
        STEP(Cf, 0, ps, 0, 3);
        STEP(Cf, 1, ps, 0, 3);
        STEP(Cf, 2, ps, 0, 3);
    }
}

extern "C" void kernel_launch(void* const* d_in, const int* in_sizes, int n_in,
                              void* d_out, int out_size, void* d_ws, size_t ws_size,
                              hipStream_t stream) {
    const float* x   = (const float*)d_in[0];   // [B, T, C] fp32
    const float* sos = (const float*)d_in[1];   // [S, 6] fp32
    float* out = (float*)d_out;                 // [B, T, C] fp32
    sos_kernel<<<NBLOCKS, BLOCK, 0, stream>>>(x, sos, out);
}

// Round 4
// 245.720 us; speedup vs baseline: 1.6801x; 1.6801x over previous
//
#include <hip/hip_runtime.h>

// SosModel: cascade of 4 biquads over T=32768, per (batch,channel); B=16, C=64.
// Overlap-save: each wave = one (batch, 64-step chunk), WARM=96 warm-up.
// For chunk k=1 the warm-up window starts at t=-32: negative rows are fed as
// ZEROS (exact: zero input from zero state keeps state zero => k=1 chunk is
// bit-exact warm-up from t=0). For k>=2, truncation ~0.9^96*gain ~1e-3 << 2.6e-2.
// lane == channel -> one contiguous 256B row load/store per wave per step.
//
// R4 vs R3 (263 us, VGPR 32, FETCH 472MB, WRITE 523MB, VALUBusy 16%):
//  launch_bounds(256,8) capped arch-VGPRs at 32 -> prefetch buffers spilled
//  to scratch -> ~730MB of garbage HBM traffic. Relax to (256,4): VGPR cap
//  128, compiler's natural ~56 regs fit 8 waves/SIMD IN HARDWARE anyway
//  (56*8=448 <= 512), so we keep the R2 TLP-doubling without forcing the
//  register allocator to guarantee it.

#define TLEN  32768
#define CCH   64
#define BATCH 16
#define NSEC  4
#define CHUNK 64
#define WARM  96         // multiple of 8; phase-1 = 12 groups = 4 x 3-rotation
#define SKEW  3          // NSEC-1 pipeline delay

#define NCHUNKS (TLEN / CHUNK)          // 512
#define NWAVES  (BATCH * NCHUNKS)       // 8192
#define BLOCK   256
#define NBLOCKS (NWAVES * 64 / BLOCK)   // 2048 -> 8 blocks/CU, 32 waves/CU

// Issue 8 row loads for group G into buffer NB.
// Negative group (only k=1 warm-up, rows -32..-1): zero-fill == exact zero
// input before t=0. High clamp: only the last chunk, and clamped rows
// provably never reach a stored output (o3 at iter i depends on inputs at
// iters <= i-3; last stored iter consumes input row <= TLEN-1).
#define ISSUE(NB, G) do {                                                     \
    int rb_ = s0 + 8 * (G);                                                   \
    if (rb_ < 0) {                                                            \
        NB[0] = NB[1] = NB[2] = NB[3] = 0.0f;                                 \
        NB[4] = NB[5] = NB[6] = NB[7] = 0.0f;                                 \
    } else {                                                                  \
        rb_ = (rb_ > TLEN - 8) ? (TLEN - 8) : rb_;                            \
        const float* __restrict__ p_ = xb + (size_t)rb_ * CCH;                \
        NB[0] = p_[0 * CCH]; NB[1] = p_[1 * CCH];                             \
        NB[2] = p_[2 * CCH]; NB[3] = p_[3 * CCH];                             \
        NB[4] = p_[4 * CCH]; NB[5] = p_[5 * CCH];                             \
        NB[6] = p_[6 * CCH]; NB[7] = p_[7 * CCH];                             \
    }                                                                         \
} while (0)

// One skewed-pipeline step; store predicate (SB <= j < SE) is compile-time.
#define STEP(CB, j, ps, SB, SE) do {                                          \
    const float i0 = CB[j], i1 = lat1, i2 = lat2, i3 = lat3;                  \
    const float p0 = fmaf(cb0[0], i0, fmaf(cb1[0], x1[0], cb2[0] * x2[0]));   \
    const float p1 = fmaf(cb0[1], i1, fmaf(cb1[1], x1[1], cb2[1] * x2[1]));   \
    const float p2 = fmaf(cb0[2], i2, fmaf(cb1[2], x1[2], cb2[2] * x2[2]));   \
    const float p3 = fmaf(cb0[3], i3, fmaf(cb1[3], x1[3], cb2[3] * x2[3]));   \
    const float o0 = fmaf(ca1[0], y1v[0], fmaf(ca2[0], y2v[0], p0));          \
    const float o1 = fmaf(ca1[1], y1v[1], fmaf(ca2[1], y2v[1], p1));          \
    const float o2 = fmaf(ca1[2], y1v[2], fmaf(ca2[2], y2v[2], p2));          \
    const float o3 = fmaf(ca1[3], y1v[3], fmaf(ca2[3], y2v[3], p3));          \
    x2[0] = x1[0]; x1[0] = i0;  y2v[0] = y1v[0]; y1v[0] = o0;                 \
    x2[1] = x1[1]; x1[1] = i1;  y2v[1] = y1v[1]; y1v[1] = o1;                 \
    x2[2] = x1[2]; x1[2] = i2;  y2v[2] = y1v[2]; y1v[2] = o2;                 \
    x2[3] = x1[3]; x1[3] = i3;  y2v[3] = y1v[3]; y1v[3] = o3;                 \
    lat1 = o0; lat2 = o1; lat3 = o2;                                          \
    if ((j) >= (SB) && (j) < (SE)) ps[(j) * CCH] = o3;                        \
} while (0)

// Full group: prefetch group G+2 into NB, compute 8 steps from CB,
// store rows per compile-time mask. H = group index within the store phase
// (store row for (H,j) is 8*H - 3 + j relative to py).
#define GROUP(CB, NB, G, H, SB, SE) do {                                      \
    ISSUE(NB, (G) + 2);                                                       \
    float* __restrict__ ps = py + (ptrdiff_t)(8 * (H) - 3) * CCH;             \
    STEP(CB, 0, ps, SB, SE); STEP(CB, 1, ps, SB, SE);                         \
    STEP(CB, 2, ps, SB, SE); STEP(CB, 3, ps, SB, SE);                         \
    STEP(CB, 4, ps, SB, SE); STEP(CB, 5, ps, SB, SE);                         \
    STEP(CB, 6, ps, SB, SE); STEP(CB, 7, ps, SB, SE);                         \
} while (0)

// Same, but no prefetch (used where the prefetch target is never consumed).
#define GROUP_NOPF(CB, H, SB, SE) do {                                        \
    float* __restrict__ ps = py + (ptrdiff_t)(8 * (H) - 3) * CCH;             \
    STEP(CB, 0, ps, SB, SE); STEP(CB, 1, ps, SB, SE);                         \
    STEP(CB, 2, ps, SB, SE); STEP(CB, 3, ps, SB, SE);                         \
    STEP(CB, 4, ps, SB, SE); STEP(CB, 5, ps, SB, SE);                         \
    STEP(CB, 6, ps, SB, SE); STEP(CB, 7, ps, SB, SE);                         \
} while (0)

__global__ __launch_bounds__(BLOCK, 4) void sos_kernel(const float* __restrict__ x,
                                                       const float* __restrict__ sos,
                                                       float* __restrict__ out) {
    const int lane = threadIdx.x & 63;                      // channel
    // Force wave-uniformity so all chunk/row math lands on the scalar pipe.
    const int wid  = __builtin_amdgcn_readfirstlane(
                         blockIdx.x * (BLOCK >> 6) + (threadIdx.x >> 6));
    const int b    = wid >> 9;                              // wid / NCHUNKS
    const int k    = wid & (NCHUNKS - 1);
    const int t0   = k * CHUNK;
    const int warm = k ? WARM : 0;
    const int s0   = t0 - warm;                             // -32 only when k==1

    const float* __restrict__ xb = x + (size_t)b * TLEN * CCH + lane;
    float* __restrict__ py = out + ((size_t)b * TLEN + (size_t)t0) * CCH + lane;

    // Prime the pipeline: groups 0 and 1 in flight before anything else.
    float Af[8], Bf[8], Cf[8];
    ISSUE(Af, 0);
    ISSUE(Bf, 1);

    // Coefficients (wave-uniform -> SGPRs); honor /a0 though a0==1 here.
    float cb0[NSEC], cb1[NSEC], cb2[NSEC], ca1[NSEC], ca2[NSEC];
    float x1[NSEC], x2[NSEC], y1v[NSEC], y2v[NSEC];
#pragma unroll
    for (int s = 0; s < NSEC; ++s) {
        const float inva = 1.0f / sos[s * 6 + 3];
        cb0[s] =  sos[s * 6 + 0] * inva;
        cb1[s] =  sos[s * 6 + 1] * inva;
        cb2[s] =  sos[s * 6 + 2] * inva;
        ca1[s] = -sos[s * 6 + 4] * inva;
        ca2[s] = -sos[s * 6 + 5] * inva;
        x1[s] = x2[s] = y1v[s] = y2v[s] = 0.0f;
    }
    float lat1 = 0.0f, lat2 = 0.0f, lat3 = 0.0f;   // inter-section pipeline latches

    int g = 0;
    // Phase 1 (chunks k>=1 only): 12 warm-up groups, no stores.
    if (warm) {
#pragma unroll 1
        for (int t = 0; t < 4; ++t) {
            GROUP(Af, Cf, g + 0, 0, 0, 0);
            GROUP(Bf, Af, g + 1, 0, 0, 0);
            GROUP(Cf, Bf, g + 2, 0, 0, 0);
            g += 3;
        }
    }
    // Phase 2: first store group (skew head): store j=3..7 -> rows 0..4.
    GROUP(Af, Cf, g + 0, 0, 3, 8);
    // Phase 3: 6 full-store groups -> rows 5..52, then one no-prefetch
    // full-store group -> rows 53..60 (its prefetch target is never read).
    GROUP(Bf, Af, g + 1, 1, 0, 8);
    GROUP(Cf, Bf, g + 2, 2, 0, 8);
    GROUP(Af, Cf, g + 3, 3, 0, 8);
    GROUP(Bf, Af, g + 4, 4, 0, 8);
    GROUP(Cf, Bf, g + 5, 5, 0, 8);
    GROUP(Af, Cf, g + 6, 6, 0, 8);
    GROUP_NOPF(Bf, 7, 0, 8);
    // Phase 4 (skew tail): store j=0..2 -> rows 61..63 from group g+8 (in Cf).
    {
        float* __restrict__ ps = py + (ptrdiff_t)(8 * 8 - 3) * CCH;
        STEP(Cf, 0, ps, 0, 3);
        STEP(Cf, 1, ps, 0, 3);
        STEP(Cf, 2, ps, 0, 3);
    }
}

extern "C" void kernel_launch(void* const* d_in, const int* in_sizes, int n_in,
                              void* d_out, int out_size, void* d_ws, size_t ws_size,
                              hipStream_t stream) {
    const float* x   = (const float*)d_in[0];   // [B, T, C] fp32
    const float* sos = (const float*)d_in[1];   // [S, 6] fp32
    float* out = (float*)d_out;                 // [B, T, C] fp32
    sos_kernel<<<NBLOCKS, BLOCK, 0, stream>>>(x, sos, out);
}

// Round 5
// 244.246 us; speedup vs baseline: 1.6903x; 1.0060x over previous
//
#include <hip/hip_runtime.h>

// SosModel: cascade of 4 biquads over T=32768, per (batch,channel); B=16, C=64.
// Wave = one (batch, 64-step chunk), uniform WARM=96 for ALL chunks (pre-t0
// rows loaded clamped and masked to 0 -> exact zero-input warm-up; k>=2
// truncation ~0.9^96*gain ~1e-3 << 2.6e-2). lane == channel.
//
// R5 vs R4 (95 us, VALUBusy 44%, HBM 3.1 TB/s plateau across 3 configs):
//  diagnosis = 256B/instr VMEM requests cap BW ~3 TB/s (m13's 6.3 TB/s is
//  1KB/instr float4). This version moves 1KB per VMEM instruction both ways:
//   - loads: global_load_lds width-16 (1 instr = 4 rows), per-wave 4-slot
//     LDS ring, prefetch distance 3, counted s_waitcnt vmcnt(N) per group.
//   - stores: stage 8 rows in the freed ring slot (ds_write_b32), read back
//     ds_read_b128 (lane -> 4 consecutive channels), global_store_dwordx4.
//  LDS 32KB/block -> 5 blocks/CU = 20 waves/CU. VGPR ~40 (buffers in LDS).

#define TLEN  32768
#define CCH   64
#define BATCH 16
#define NSEC  4
#define CHUNK 64
#define WARM  96

#define NCHUNKS (TLEN / CHUNK)          // 512
#define NWAVES  (BATCH * NCHUNKS)       // 8192
#define BLOCK   256
#define NBLOCKS (NWAVES * 64 / BLOCK)   // 2048

// ---- async global->LDS, 16B per lane (1KB = 4 rows per call) --------------
#define GLL(gp, lp)                                                           \
    __builtin_amdgcn_global_load_lds(                                         \
        (const __attribute__((address_space(1))) void*)(gp),                  \
        (__attribute__((address_space(3))) void*)(lp), 16, 0, 0)

#define WAITV_IMPL(N) asm volatile("s_waitcnt vmcnt(" #N ")" ::: "memory")
#define WAITV(N) WAITV_IMPL(N)

// Issue 8-row group G into ring slot pointed by lp (wave-uniform).
// Row base clamped to [0, TLEN-8]: negative rows (warm-up before t=0) are
// consumed with a 0-mask; high clamp only on the last chunk's dead tail.
#define ISSUE(G, lp) do {                                                     \
    int rb_ = s0 + 8 * (G);                                                   \
    rb_ = rb_ < 0 ? 0 : rb_;                                                  \
    rb_ = rb_ > TLEN - 8 ? TLEN - 8 : rb_;                                    \
    const float* gp_ = xb4 + (size_t)rb_ * CCH + (lane << 2);                 \
    GLL(gp_, (lp));                                                           \
    GLL(gp_ + 256, (lp) + 256);                                               \
} while (0)

// ---- biquad cascade core (skewed pipeline, 1 loop-carried FMA/section) ----
#define FBODY(xin)                                                            \
    const float i0 = (xin), i1 = lat1, i2 = lat2, i3 = lat3;                  \
    const float p0 = fmaf(cb0[0], i0, fmaf(cb1[0], x1[0], cb2[0] * x2[0]));   \
    const float p1 = fmaf(cb0[1], i1, fmaf(cb1[1], x1[1], cb2[1] * x2[1]));   \
    const float p2 = fmaf(cb0[2], i2, fmaf(cb1[2], x1[2], cb2[2] * x2[2]));   \
    const float p3 = fmaf(cb0[3], i3, fmaf(cb1[3], x1[3], cb2[3] * x2[3]));   \
    const float o0 = fmaf(ca1[0], y1v[0], fmaf(ca2[0], y2v[0], p0));          \
    const float o1 = fmaf(ca1[1], y1v[1], fmaf(ca2[1], y2v[1], p1));          \
    const float o2 = fmaf(ca1[2], y1v[2], fmaf(ca2[2], y2v[2], p2));          \
    const float o3 = fmaf(ca1[3], y1v[3], fmaf(ca2[3], y2v[3], p3));          \
    x2[0] = x1[0]; x1[0] = i0;  y2v[0] = y1v[0]; y1v[0] = o0;                 \
    x2[1] = x1[1]; x1[1] = i1;  y2v[1] = y1v[1]; y1v[1] = o1;                 \
    x2[2] = x1[2]; x1[2] = i2;  y2v[2] = y1v[2]; y1v[2] = o2;                 \
    x2[3] = x1[3]; x1[3] = i3;  y2v[3] = y1v[3]; y1v[3] = o3;                 \
    lat1 = o0; lat2 = o1; lat3 = o2;

#define STEP_NS(xin)            do { FBODY(xin); (void)o3; } while (0)
#define STEP_STAGE(xin, SL, q)  do { FBODY(xin); ring[(SL)*512 + (q)*64 + lane] = o3; } while (0)
#define STEP_DW(xin, r)         do { FBODY(xin); po[(size_t)(r) * CCH] = o3; } while (0)

// ds_read_b128 the 4 staged rows starting at q0, store 1KB contiguous.
#define FLUSH4(SL, q0, r0) do {                                               \
    const float4 v_ = *(const float4*)&ring[(SL)*512 + (q0)*64 + lane*4];     \
    *(float4*)&pq[(size_t)(r0) * CCH] = v_;                                   \
} while (0)

#define READ8(SL)                                                             \
    xr[0] = ring[(SL)*512 + 0*64 + lane];                                     \
    xr[1] = ring[(SL)*512 + 1*64 + lane];                                     \
    xr[2] = ring[(SL)*512 + 2*64 + lane];                                     \
    xr[3] = ring[(SL)*512 + 3*64 + lane];                                     \
    xr[4] = ring[(SL)*512 + 4*64 + lane];                                     \
    xr[5] = ring[(SL)*512 + 5*64 + lane];                                     \
    xr[6] = ring[(SL)*512 + 6*64 + lane];                                     \
    xr[7] = ring[(SL)*512 + 7*64 + lane];

// Warm group (no stores); u = literal slot (g & 3), g = 4t+u. Mask zeroes
// pre-t0 rows (exact). vmcnt(6) = loads of groups g+1..g+3 outstanding.
#define WGROUP(u, g) do {                                                     \
    ISSUE((g) + 3, ring + (((u) + 3) & 3) * 512);                             \
    WAITV(6);                                                                 \
    float xr[8];                                                              \
    READ8(u);                                                                 \
    const float wm_ = (s0 + 8 * (g) >= 0) ? 1.0f : 0.0f;                      \
    STEP_NS(xr[0] * wm_); STEP_NS(xr[1] * wm_);                               \
    STEP_NS(xr[2] * wm_); STEP_NS(xr[3] * wm_);                               \
    STEP_NS(xr[4] * wm_); STEP_NS(xr[5] * wm_);                               \
    STEP_NS(xr[6] * wm_); STEP_NS(xr[7] * wm_);                               \
} while (0)

// Full-store group: stage 8 rows into the slot just consumed, flush as two
// 1KB dwordx4 stores. NW = exact outstanding-VMEM count (derivation in notes).
#define SGROUP(G, SL, SLI, NW, r0) do {                                       \
    ISSUE((G) + 3, ring + (SLI) * 512);                                       \
    WAITV(NW);                                                                \
    float xr[8];                                                              \
    READ8(SL);                                                                \
    STEP_STAGE(xr[0], SL, 0); STEP_STAGE(xr[1], SL, 1);                       \
    STEP_STAGE(xr[2], SL, 2); STEP_STAGE(xr[3], SL, 3);                       \
    STEP_STAGE(xr[4], SL, 4); STEP_STAGE(xr[5], SL, 5);                       \
    STEP_STAGE(xr[6], SL, 6); STEP_STAGE(xr[7], SL, 7);                       \
    FLUSH4(SL, 0, r0); FLUSH4(SL, 4, (r0) + 4);                               \
} while (0)

#define SGROUP_NOPF(G, SL, NW, r0) do {                                       \
    WAITV(NW);                                                                \
    float xr[8];                                                              \
    READ8(SL);                                                                \
    STEP_STAGE(xr[0], SL, 0); STEP_STAGE(xr[1], SL, 1);                       \
    STEP_STAGE(xr[2], SL, 2); STEP_STAGE(xr[3], SL, 3);                       \
    STEP_STAGE(xr[4], SL, 4); STEP_STAGE(xr[5], SL, 5);                       \
    STEP_STAGE(xr[6], SL, 6); STEP_STAGE(xr[7], SL, 7);                       \
    FLUSH4(SL, 0, r0); FLUSH4(SL, 4, (r0) + 4);                               \
} while (0)

__global__ __launch_bounds__(BLOCK, 4) void sos_kernel(const float* __restrict__ x,
                                                       const float* __restrict__ sos,
                                                       float* __restrict__ out) {
    __shared__ alignas(16) float smem[4 * 4 * 512];       // 4 waves x 4 slots x 2KB
    const int lane = threadIdx.x & 63;                    // channel
    const int warp = threadIdx.x >> 6;
    const int wid  = __builtin_amdgcn_readfirstlane(blockIdx.x * (BLOCK >> 6) + warp);
    const int b    = wid >> 9;                            // wid / NCHUNKS
    const int k    = wid & (NCHUNKS - 1);
    const int t0   = k * CHUNK;
    const int s0   = t0 - WARM;                           // uniform for ALL waves

    float* __restrict__ ring = smem + warp * 2048;        // this wave's ring
    const float* __restrict__ xb4 = x + (size_t)b * TLEN * CCH;         // no lane
    float* __restrict__ po = out + ((size_t)b * TLEN + t0) * CCH + lane;     // dword
    float* __restrict__ pq = out + ((size_t)b * TLEN + t0) * CCH + lane * 4; // dwordx4

    // Coefficients (wave-uniform -> SGPRs); honor /a0 though a0==1 here.
    float cb0[NSEC], cb1[NSEC], cb2[NSEC], ca1[NSEC], ca2[NSEC];
    float x1[NSEC], x2[NSEC], y1v[NSEC], y2v[NSEC];
#pragma unroll
    for (int s = 0; s < NSEC; ++s) {
        const float inva = 1.0f / sos[s * 6 + 3];
        cb0[s] =  sos[s * 6 + 0] * inva;
        cb1[s] =  sos[s * 6 + 1] * inva;
        cb2[s] =  sos[s * 6 + 2] * inva;
        ca1[s] = -sos[s * 6 + 4] * inva;
        ca2[s] = -sos[s * 6 + 5] * inva;
        x1[s] = x2[s] = y1v[s] = y2v[s] = 0.0f;
    }
    float lat1 = 0.0f, lat2 = 0.0f, lat3 = 0.0f;          // inter-section latches

    // Keep coefficient loads strictly before the ring loads (fixed vmcnt math).
    asm volatile("" ::: "memory");

    // Prime: groups 0..2 -> slots 0..2 (distance-3 pipeline).
    ISSUE(0, ring + 0 * 512);
    ISSUE(1, ring + 1 * 512);
    ISSUE(2, ring + 2 * 512);

    // Phase 1: 12 warm groups (i = 0..95), no stores. slot = g & 3.
#pragma unroll 1
    for (int t = 0; t < 12; t += 4) {
        WGROUP(0, t + 0);
        WGROUP(1, t + 1);
        WGROUP(2, t + 2);
        WGROUP(3, t + 3);
    }

    // Phase 2: group 12 (i=96..103): j=3..6 staged -> rows 0..3 (1KB store),
    // j=7 -> row 4 (dword). 2 store ops.
    {
        ISSUE(15, ring + 3 * 512);
        WAITV(6);
        float xr[8];
        READ8(0);
        STEP_NS(xr[0]); STEP_NS(xr[1]); STEP_NS(xr[2]);
        STEP_STAGE(xr[3], 0, 3); STEP_STAGE(xr[4], 0, 4);
        STEP_STAGE(xr[5], 0, 5); STEP_STAGE(xr[6], 0, 6);
        STEP_DW(xr[7], 4);
        FLUSH4(0, 3, 0);
    }

    // Phase 3: full-store groups 13..19 -> rows 5..60 (two 1KB stores each).
    SGROUP(13, 1, 0, 8,  5);
    SGROUP(14, 2, 1, 10, 13);
    SGROUP(15, 3, 2, 12, 21);
    SGROUP(16, 0, 3, 12, 29);
    SGROUP(17, 1, 0, 12, 37);
    SGROUP_NOPF(18, 2, 10, 45);
    SGROUP_NOPF(19, 3, 8, 53);

    // Phase 4: group 20, only j=0..2 (i=160..162) -> rows 61..63 (dword).
    {
        WAITV(6);
        float xr0 = ring[0 * 512 + 0 * 64 + lane];
        float xr1 = ring[0 * 512 + 1 * 64 + lane];
        float xr2 = ring[0 * 512 + 2 * 64 + lane];
        STEP_DW(xr0, 61);
        STEP_DW(xr1, 62);
        STEP_DW(xr2, 63);
    }
}

extern "C" void kernel_launch(void* const* d_in, const int* in_sizes, int n_in,
                              void* d_out, int out_size, void* d_ws, size_t ws_size,
                              hipStream_t stream) {
    const float* x   = (const float*)d_in[0];   // [B, T, C] fp32
    const float* sos = (const float*)d_in[1];   // [S, 6] fp32
    float* out = (float*)d_out;                 // [B, T, C] fp32
    sos_kernel<<<NBLOCKS, BLOCK, 0, stream>>>(x, sos, out);
}

// Round 8
// 243.257 us; speedup vs baseline: 1.6971x; 1.0041x over previous
//
#include <hip/hip_runtime.h>

// SosModel: cascade of 4 biquads over T=32768, per (batch,channel); B=16, C=64.
// Wave = one (batch, 64-step chunk), uniform WARM=96 for ALL chunks (pre-t0
// rows clamped to row 0 and masked by a wave-uniform 0.0 -> exact zero-input
// warm-up; k>=2 truncation ~0.9^96*gain ~1e-3 << 2.6e-2). lane == channel.
//
// R8 == R6 resubmitted (3rd attempt): R6/R7 benches died at container
// acquisition ("MI355X container failed twice" -- no pytest traceback, no
// compile output, no counters => infra, not kernel). The store-decoupling
// theory is still unmeasured. Kernel has no loops/barriers -> cannot hang.
//
// THEORY (from R5's 92.6 us / 3.28 TB/s plateau across 3 structures):
//  gfx9 global stores increment vmcnt, and vmcnt retires IN ORDER.
//  Every prior version interleaved stores between load-issue and load-wait,
//  so each group's load-wait transitively waited for stores ~2 groups old to
//  retire -> group period ~ store-ack latency (~2k cy), not compute (~400 cy).
//  FIX: no store is issued until after the LAST load-wait. All 64 output rows
//  accumulate in VGPRs (yout[64], compile-time indices only); the 21-group
//  main loop has loads only (3-buffer, distance-2 register prefetch, compiler
//  emits exact vmcnt per consume); epilogue fires 64 fire-and-forget
//  global_store_dword with no wait before endpgm. No LDS.

#define TLEN  32768
#define CCH   64
#define NSEC  4
#define CHUNK 64
#define WARM  96

#define NCHUNKS (TLEN / CHUNK)          // 512
#define NWAVES  (16 * NCHUNKS)          // 8192
#define BLOCK   256
#define NBLOCKS (NWAVES * 64 / BLOCK)   // 2048

// Load the 8 rows of group G into register buffer NB (8 x 256B dword loads).
// Low clamp: pre-t0 warm rows (masked to zero at consume -> exact).
// High clamp: only the last chunk's pipeline tail; clamped rows feed only
// section-0..2 state for times > T-1, which never reaches a stored output.
#define ISSUE(NB, G) do {                                                     \
    int rb_ = s0 + 8 * (G);                                                   \
    rb_ = rb_ < 0 ? 0 : rb_;                                                  \
    rb_ = rb_ > TLEN - 8 ? TLEN - 8 : rb_;                                    \
    const float* __restrict__ p_ = xb + (size_t)rb_ * CCH;                    \
    NB[0] = p_[0 * CCH]; NB[1] = p_[1 * CCH];                                 \
    NB[2] = p_[2 * CCH]; NB[3] = p_[3 * CCH];                                 \
    NB[4] = p_[4 * CCH]; NB[5] = p_[5 * CCH];                                 \
    NB[6] = p_[6 * CCH]; NB[7] = p_[7 * CCH];                                 \
} while (0)

// Skewed-pipeline cascade step: section s processes time s0+i-s at iter i.
// Loop-carried dependency = 1 FMA per section (y1 -> o).
#define FBODY(xin)                                                            \
    const float i0 = (xin), i1 = lat1, i2 = lat2, i3 = lat3;                  \
    const float p0 = fmaf(cb0[0], i0, fmaf(cb1[0], x1[0], cb2[0] * x2[0]));   \
    const float p1 = fmaf(cb0[1], i1, fmaf(cb1[1], x1[1], cb2[1] * x2[1]));   \
    const float p2 = fmaf(cb0[2], i2, fmaf(cb1[2], x1[2], cb2[2] * x2[2]));   \
    const float p3 = fmaf(cb0[3], i3, fmaf(cb1[3], x1[3], cb2[3] * x2[3]));   \
    const float o0 = fmaf(ca1[0], y1v[0], fmaf(ca2[0], y2v[0], p0));          \
    const float o1 = fmaf(ca1[1], y1v[1], fmaf(ca2[1], y2v[1], p1));          \
    const float o2 = fmaf(ca1[2], y1v[2], fmaf(ca2[2], y2v[2], p2));          \
    const float o3 = fmaf(ca1[3], y1v[3], fmaf(ca2[3], y2v[3], p3));          \
    x2[0] = x1[0]; x1[0] = i0;  y2v[0] = y1v[0]; y1v[0] = o0;                 \
    x2[1] = x1[1]; x1[1] = i1;  y2v[1] = y1v[1]; y1v[1] = o1;                 \
    x2[2] = x1[2]; x1[2] = i2;  y2v[2] = y1v[2]; y1v[2] = o2;                 \
    x2[3] = x1[3]; x1[3] = i3;  y2v[3] = y1v[3]; y1v[3] = o3;                 \
    lat1 = o0; lat2 = o1; lat3 = o2;

#define STEP_NS(xin)    do { FBODY(xin); (void)o3; } while (0)
#define STEP_Y(xin, R)  do { FBODY(xin); yout[R] = o3; } while (0)   // R literal

// Warm group g (0..11): prefetch L(g+2), consume CB masked (wave-uniform 0/1).
#define WG(CB, NB, g) do {                                                    \
    ISSUE(NB, (g) + 2);                                                       \
    const float wm_ = (s0 + 8 * (g) >= 0) ? 1.0f : 0.0f;                      \
    STEP_NS(CB[0] * wm_); STEP_NS(CB[1] * wm_);                               \
    STEP_NS(CB[2] * wm_); STEP_NS(CB[3] * wm_);                               \
    STEP_NS(CB[4] * wm_); STEP_NS(CB[5] * wm_);                               \
    STEP_NS(CB[6] * wm_); STEP_NS(CB[7] * wm_);                               \
} while (0)

// Full group (13..18): prefetch L(g+2), 8 steps -> yout[R0..R0+7].
#define SG(CB, NB, g, R0) do {                                                \
    ISSUE(NB, (g) + 2);                                                       \
    STEP_Y(CB[0], (R0) + 0); STEP_Y(CB[1], (R0) + 1);                         \
    STEP_Y(CB[2], (R0) + 2); STEP_Y(CB[3], (R0) + 3);                         \
    STEP_Y(CB[4], (R0) + 4); STEP_Y(CB[5], (R0) + 5);                         \
    STEP_Y(CB[6], (R0) + 6); STEP_Y(CB[7], (R0) + 7);                         \
} while (0)

__global__ __launch_bounds__(BLOCK, 4) void sos_kernel(const float* __restrict__ x,
                                                       const float* __restrict__ sos,
                                                       float* __restrict__ out) {
    const int lane = threadIdx.x & 63;                    // channel
    const int wid  = __builtin_amdgcn_readfirstlane(
                         blockIdx.x * (BLOCK >> 6) + (threadIdx.x >> 6));
    const int b    = wid >> 9;                            // wid / NCHUNKS
    const int k    = wid & (NCHUNKS - 1);
    const int t0   = k * CHUNK;
    const int s0   = t0 - WARM;                           // uniform for ALL waves

    const float* __restrict__ xb = x + (size_t)b * TLEN * CCH + lane;
    float* __restrict__ py = out + ((size_t)b * TLEN + t0) * CCH + lane;

    // Prime the distance-2 pipeline (loads only ever touch the vmcnt FIFO
    // until the epilogue).
    float Af[8], Bf[8], Cf[8];
    ISSUE(Af, 0);
    ISSUE(Bf, 1);

    // Coefficients: wave-uniform scalar loads (lgkmcnt, not vmcnt).
    float cb0[NSEC], cb1[NSEC], cb2[NSEC], ca1[NSEC], ca2[NSEC];
    float x1[NSEC], x2[NSEC], y1v[NSEC], y2v[NSEC];
#pragma unroll
    for (int s = 0; s < NSEC; ++s) {
        const float inva = 1.0f / sos[s * 6 + 3];
        cb0[s] =  sos[s * 6 + 0] * inva;
        cb1[s] =  sos[s * 6 + 1] * inva;
        cb2[s] =  sos[s * 6 + 2] * inva;
        ca1[s] = -sos[s * 6 + 4] * inva;
        ca2[s] = -sos[s * 6 + 5] * inva;
        x1[s] = x2[s] = y1v[s] = y2v[s] = 0.0f;
    }
    float lat1 = 0.0f, lat2 = 0.0f, lat3 = 0.0f;          // inter-section latches

    float yout[64];                                       // all indices literal

    // Buffer of L(h) = h % 3 (Af=0, Bf=1, Cf=2); group h consumes h%3 and
    // issues L(h+2) into (h+2)%3 (freed last group).
    // Phase 1: warm groups 0..11 (i = 0..95), masked, no outputs.
    WG(Af, Cf, 0);  WG(Bf, Af, 1);  WG(Cf, Bf, 2);
    WG(Af, Cf, 3);  WG(Bf, Af, 4);  WG(Cf, Bf, 5);
    WG(Af, Cf, 6);  WG(Bf, Af, 7);  WG(Cf, Bf, 8);
    WG(Af, Cf, 9);  WG(Bf, Af, 10); WG(Cf, Bf, 11);

    // Phase 2: group 12 (i=96..103): j=0..2 warm tail, j=3..7 -> yout[0..4].
    {
        ISSUE(Cf, 14);
        STEP_NS(Af[0]); STEP_NS(Af[1]); STEP_NS(Af[2]);
        STEP_Y(Af[3], 0); STEP_Y(Af[4], 1); STEP_Y(Af[5], 2);
        STEP_Y(Af[6], 3); STEP_Y(Af[7], 4);
    }

    // Phase 3: groups 13..18 -> yout[5..52] (R0 = 8*(g-12)-3).
    SG(Bf, Af, 13, 5);
    SG(Cf, Bf, 14, 13);
    SG(Af, Cf, 15, 21);
    SG(Bf, Af, 16, 29);
    SG(Cf, Bf, 17, 37);
    SG(Af, Cf, 18, 45);      // issues L20 -> Cf (last load)

    // Group 19 (no prefetch): -> yout[53..60].
    {
        STEP_Y(Bf[0], 53); STEP_Y(Bf[1], 54); STEP_Y(Bf[2], 55);
        STEP_Y(Bf[3], 56); STEP_Y(Bf[4], 57); STEP_Y(Bf[5], 58);
        STEP_Y(Bf[6], 59); STEP_Y(Bf[7], 60);
    }
    // Group 20: j=0..2 (i=160..162) -> yout[61..63]. Last load-wait is here.
    {
        STEP_Y(Cf[0], 61); STEP_Y(Cf[1], 62); STEP_Y(Cf[2], 63);
    }

    // Epilogue: 64 fire-and-forget stores. Nothing waits on them (no
    // subsequent vmcnt wait before endpgm), so store retirement never
    // enters any wave's critical path.
#pragma unroll
    for (int r = 0; r < 64; ++r) {
        py[(size_t)r * CCH] = yout[r];
    }
}

extern "C" void kernel_launch(void* const* d_in, const int* in_sizes, int n_in,
                              void* d_out, int out_size, void* d_ws, size_t ws_size,
                              hipStream_t stream) {
    const float* x   = (const float*)d_in[0];   // [B, T, C] fp32
    const float* sos = (const float*)d_in[1];   // [S, 6] fp32
    float* out = (float*)d_out;                 // [B, T, C] fp32
    sos_kernel<<<NBLOCKS, BLOCK, 0, stream>>>(x, sos, out);
}

// Round 9
// 241.731 us; speedup vs baseline: 1.7079x; 1.0063x over previous
//
#include <hip/hip_runtime.h>

// SosModel: cascade of 4 biquads over T=32768, per (batch,channel); B=16, C=64.
// Wave = one (batch, 64-step chunk), uniform WARM=96 for ALL chunks (pre-t0
// rows clamped to row 0 and masked by a wave-uniform 0.0 -> exact zero-input
// warm-up; k>=2 truncation ~0.9^96*gain ~1e-3 << 2.6e-2). lane == channel.
//
// R9 vs R8 (89.6 us, VGPR 52!, VALU 49%):
//  R8's epilogue stores were SUNK into the main loop by LLVM (proof: VGPR=52
//  < 64 needed to keep yout[64] live; dur ~= interleaved-store R4). So the
//  store-decoupling theory is still unmeasured. This version makes the
//  epilogue un-sinkable:
//   - asm volatile("" ::: "memory") fence after the last load-consume
//     (stores cannot legally move above a may-read asm);
//   - stores are asm volatile global_store_dword (mutually ordered), 4 base
//     pointers x 16 literal offset: immediates;
//   - NO load-consume after any asm store (compiler can't see asm stores in
//     its vmcnt bookkeeping; a later counted load-wait would silently become
//     a wait-on-stores again). Last prefetch trimmed to the 3 consumed rows.
//  THEORY: vmcnt FIFO is in-order and shared by loads+stores; interleaving
//  stores between load-issue and load-wait couples every group's load-wait
//  to ~2-group-old store retirement -> the 3.3 TB/s plateau seen in
//  R1/R4/R5/R8. Decoupled, expect 55-70 us.
//  Counter check: VGPR ~110-125 proves the epilogue survived; VGPR ~52 means
//  fence failed; VGPR >=128 + FETCH balloon means spill.

#define TLEN  32768
#define CCH   64
#define NSEC  4
#define CHUNK 64
#define WARM  96

#define NCHUNKS (TLEN / CHUNK)          // 512
#define NWAVES  (16 * NCHUNKS)          // 8192
#define BLOCK   256
#define NBLOCKS (NWAVES * 64 / BLOCK)   // 2048

// Load the 8 rows of group G into register buffer NB (8 x 256B dword loads).
// Low clamp: pre-t0 warm rows (masked to zero at consume -> exact).
// High clamp: only the last chunk's pipeline tail; clamped rows feed only
// section-0..2 state for times > T-1, which never reaches a stored output.
#define ISSUE(NB, G) do {                                                     \
    int rb_ = s0 + 8 * (G);                                                   \
    rb_ = rb_ < 0 ? 0 : rb_;                                                  \
    rb_ = rb_ > TLEN - 8 ? TLEN - 8 : rb_;                                    \
    const float* __restrict__ p_ = xb + (size_t)rb_ * CCH;                    \
    NB[0] = p_[0 * CCH]; NB[1] = p_[1 * CCH];                                 \
    NB[2] = p_[2 * CCH]; NB[3] = p_[3 * CCH];                                 \
    NB[4] = p_[4 * CCH]; NB[5] = p_[5 * CCH];                                 \
    NB[6] = p_[6 * CCH]; NB[7] = p_[7 * CCH];                                 \
} while (0)

// Last prefetch: only rows 0..2 of group G are ever consumed (group 20).
#define ISSUE3(NB, G) do {                                                    \
    int rb_ = s0 + 8 * (G);                                                   \
    rb_ = rb_ < 0 ? 0 : rb_;                                                  \
    rb_ = rb_ > TLEN - 8 ? TLEN - 8 : rb_;                                    \
    const float* __restrict__ p_ = xb + (size_t)rb_ * CCH;                    \
    NB[0] = p_[0 * CCH]; NB[1] = p_[1 * CCH]; NB[2] = p_[2 * CCH];            \
} while (0)

// Skewed-pipeline cascade step: section s processes time s0+i-s at iter i.
// Loop-carried dependency = 1 FMA per section (y1 -> o).
#define FBODY(xin)                                                            \
    const float i0 = (xin), i1 = lat1, i2 = lat2, i3 = lat3;                  \
    const float p0 = fmaf(cb0[0], i0, fmaf(cb1[0], x1[0], cb2[0] * x2[0]));   \
    const float p1 = fmaf(cb0[1], i1, fmaf(cb1[1], x1[1], cb2[1] * x2[1]));   \
    const float p2 = fmaf(cb0[2], i2, fmaf(cb1[2], x1[2], cb2[2] * x2[2]));   \
    const float p3 = fmaf(cb0[3], i3, fmaf(cb1[3], x1[3], cb2[3] * x2[3]));   \
    const float o0 = fmaf(ca1[0], y1v[0], fmaf(ca2[0], y2v[0], p0));          \
    const float o1 = fmaf(ca1[1], y1v[1], fmaf(ca2[1], y2v[1], p1));          \
    const float o2 = fmaf(ca1[2], y1v[2], fmaf(ca2[2], y2v[2], p2));          \
    const float o3 = fmaf(ca1[3], y1v[3], fmaf(ca2[3], y2v[3], p3));          \
    x2[0] = x1[0]; x1[0] = i0;  y2v[0] = y1v[0]; y1v[0] = o0;                 \
    x2[1] = x1[1]; x1[1] = i1;  y2v[1] = y1v[1]; y1v[1] = o1;                 \
    x2[2] = x1[2]; x1[2] = i2;  y2v[2] = y1v[2]; y1v[2] = o2;                 \
    x2[3] = x1[3]; x1[3] = i3;  y2v[3] = y1v[3]; y1v[3] = o3;                 \
    lat1 = o0; lat2 = o1; lat3 = o2;

#define STEP_NS(xin)    do { FBODY(xin); (void)o3; } while (0)
#define STEP_Y(xin, R)  do { FBODY(xin); yout[R] = o3; } while (0)   // R literal

// Warm group g (0..11): prefetch L(g+2), consume CB masked (wave-uniform 0/1).
#define WG(CB, NB, g) do {                                                    \
    ISSUE(NB, (g) + 2);                                                       \
    const float wm_ = (s0 + 8 * (g) >= 0) ? 1.0f : 0.0f;                      \
    STEP_NS(CB[0] * wm_); STEP_NS(CB[1] * wm_);                               \
    STEP_NS(CB[2] * wm_); STEP_NS(CB[3] * wm_);                               \
    STEP_NS(CB[4] * wm_); STEP_NS(CB[5] * wm_);                               \
    STEP_NS(CB[6] * wm_); STEP_NS(CB[7] * wm_);                               \
} while (0)

// Full group: prefetch L(g+2), 8 steps -> yout[R0..R0+7].
#define SG(CB, NB, g, R0) do {                                                \
    ISSUE(NB, (g) + 2);                                                       \
    STEP_Y(CB[0], (R0) + 0); STEP_Y(CB[1], (R0) + 1);                         \
    STEP_Y(CB[2], (R0) + 2); STEP_Y(CB[3], (R0) + 3);                         \
    STEP_Y(CB[4], (R0) + 4); STEP_Y(CB[5], (R0) + 5);                         \
    STEP_Y(CB[6], (R0) + 6); STEP_Y(CB[7], (R0) + 7);                         \
} while (0)

// Volatile asm store: ordered after the fence and w.r.t. each other; the
// compiler cannot sink these into the load loop. OFF must be a literal.
#define AST_(BP, OFF, V)                                                      \
    asm volatile("global_store_dword %0, %1, off offset:" #OFF                \
                 :: "v"(BP), "v"(V))
#define AST(BP, OFF, V) AST_(BP, OFF, V)

__global__ __launch_bounds__(BLOCK, 4) void sos_kernel(const float* __restrict__ x,
                                                       const float* __restrict__ sos,
                                                       float* __restrict__ out) {
    const int lane = threadIdx.x & 63;                    // channel
    const int wid  = __builtin_amdgcn_readfirstlane(
                         blockIdx.x * (BLOCK >> 6) + (threadIdx.x >> 6));
    const int b    = wid >> 9;                            // wid / NCHUNKS
    const int k    = wid & (NCHUNKS - 1);
    const int t0   = k * CHUNK;
    const int s0   = t0 - WARM;                           // uniform for ALL waves

    const float* __restrict__ xb = x + (size_t)b * TLEN * CCH + lane;
    float* __restrict__ py = out + ((size_t)b * TLEN + t0) * CCH + lane;

    // Prime the distance-2 pipeline (loads only in the vmcnt FIFO until the
    // epilogue).
    float Af[8], Bf[8], Cf[8];
    ISSUE(Af, 0);
    ISSUE(Bf, 1);

    // Coefficients (wave-uniform); honor /a0 though a0==1 here.
    float cb0[NSEC], cb1[NSEC], cb2[NSEC], ca1[NSEC], ca2[NSEC];
    float x1[NSEC], x2[NSEC], y1v[NSEC], y2v[NSEC];
#pragma unroll
    for (int s = 0; s < NSEC; ++s) {
        const float inva = 1.0f / sos[s * 6 + 3];
        cb0[s] =  sos[s * 6 + 0] * inva;
        cb1[s] =  sos[s * 6 + 1] * inva;
        cb2[s] =  sos[s * 6 + 2] * inva;
        ca1[s] = -sos[s * 6 + 4] * inva;
        ca2[s] = -sos[s * 6 + 5] * inva;
        x1[s] = x2[s] = y1v[s] = y2v[s] = 0.0f;
    }
    float lat1 = 0.0f, lat2 = 0.0f, lat3 = 0.0f;          // inter-section latches

    float yout[64];                                       // all indices literal

    // Buffer of L(h) = h % 3 (Af=0, Bf=1, Cf=2); group h consumes h%3 and
    // issues L(h+2) into (h+2)%3 (freed last group).
    // Phase 1: warm groups 0..11 (i = 0..95), masked, no outputs.
    WG(Af, Cf, 0);  WG(Bf, Af, 1);  WG(Cf, Bf, 2);
    WG(Af, Cf, 3);  WG(Bf, Af, 4);  WG(Cf, Bf, 5);
    WG(Af, Cf, 6);  WG(Bf, Af, 7);  WG(Cf, Bf, 8);
    WG(Af, Cf, 9);  WG(Bf, Af, 10); WG(Cf, Bf, 11);

    // Phase 2: group 12 (i=96..103): j=0..2 warm tail, j=3..7 -> yout[0..4].
    {
        ISSUE(Cf, 14);
        STEP_NS(Af[0]); STEP_NS(Af[1]); STEP_NS(Af[2]);
        STEP_Y(Af[3], 0); STEP_Y(Af[4], 1); STEP_Y(Af[5], 2);
        STEP_Y(Af[6], 3); STEP_Y(Af[7], 4);
    }

    // Phase 3: groups 13..18 -> yout[5..52] (R0 = 8*(g-12)-3).
    SG(Bf, Af, 13, 5);
    SG(Cf, Bf, 14, 13);
    SG(Af, Cf, 15, 21);
    SG(Bf, Af, 16, 29);
    SG(Cf, Bf, 17, 37);
    // Group 18: last prefetch (L20), trimmed to the 3 rows group 20 consumes.
    {
        ISSUE3(Cf, 20);
        STEP_Y(Af[0], 45); STEP_Y(Af[1], 46); STEP_Y(Af[2], 47);
        STEP_Y(Af[3], 48); STEP_Y(Af[4], 49); STEP_Y(Af[5], 50);
        STEP_Y(Af[6], 51); STEP_Y(Af[7], 52);
    }

    // Group 19 (no prefetch): -> yout[53..60].
    {
        STEP_Y(Bf[0], 53); STEP_Y(Bf[1], 54); STEP_Y(Bf[2], 55);
        STEP_Y(Bf[3], 56); STEP_Y(Bf[4], 57); STEP_Y(Bf[5], 58);
        STEP_Y(Bf[6], 59); STEP_Y(Bf[7], 60);
    }
    // Group 20: j=0..2 (i=160..162) -> yout[61..63]. LAST load-wait is here.
    {
        STEP_Y(Cf[0], 61); STEP_Y(Cf[1], 62); STEP_Y(Cf[2], 63);
    }

    // ---- un-sinkable epilogue -------------------------------------------
    // Fence: stores below may not move above (asm may read memory).
    asm volatile("" ::: "memory");
    float* q0 = py;
    float* q1 = py + 16 * CCH;
    float* q2 = py + 32 * CCH;
    float* q3 = py + 48 * CCH;
    AST(q0,    0, yout[ 0]); AST(q0,  256, yout[ 1]); AST(q0,  512, yout[ 2]); AST(q0,  768, yout[ 3]);
    AST(q0, 1024, yout[ 4]); AST(q0, 1280, yout[ 5]); AST(q0, 1536, yout[ 6]); AST(q0, 1792, yout[ 7]);
    AST(q0, 2048, yout[ 8]); AST(q0, 2304, yout[ 9]); AST(q0, 2560, yout[10]); AST(q0, 2816, yout[11]);
    AST(q0, 3072, yout[12]); AST(q0, 3328, yout[13]); AST(q0, 3584, yout[14]); AST(q0, 3840, yout[15]);
    AST(q1,    0, yout[16]); AST(q1,  256, yout[17]); AST(q1,  512, yout[18]); AST(q1,  768, yout[19]);
    AST(q1, 1024, yout[20]); AST(q1, 1280, yout[21]); AST(q1, 1536, yout[22]); AST(q1, 1792, yout[23]);
    AST(q1, 2048, yout[24]); AST(q1, 2304, yout[25]); AST(q1, 2560, yout[26]); AST(q1, 2816, yout[27]);
    AST(q1, 3072, yout[28]); AST(q1, 3328, yout[29]); AST(q1, 3584, yout[30]); AST(q1, 3840, yout[31]);
    AST(q2,    0, yout[32]); AST(q2,  256, yout[33]); AST(q2,  512, yout[34]); AST(q2,  768, yout[35]);
    AST(q2, 1024, yout[36]); AST(q2, 1280, yout[37]); AST(q2, 1536, yout[38]); AST(q2, 1792, yout[39]);
    AST(q2, 2048, yout[40]); AST(q2, 2304, yout[41]); AST(q2, 2560, yout[42]); AST(q2, 2816, yout[43]);
    AST(q2, 3072, yout[44]); AST(q2, 3328, yout[45]); AST(q2, 3584, yout[46]); AST(q2, 3840, yout[47]);
    AST(q3,    0, yout[48]); AST(q3,  256, yout[49]); AST(q3,  512, yout[50]); AST(q3,  768, yout[51]);
    AST(q3, 1024, yout[52]); AST(q3, 1280, yout[53]); AST(q3, 1536, yout[54]); AST(q3, 1792, yout[55]);
    AST(q3, 2048, yout[56]); AST(q3, 2304, yout[57]); AST(q3, 2560, yout[58]); AST(q3, 2816, yout[59]);
    AST(q3, 3072, yout[60]); AST(q3, 3328, yout[61]); AST(q3, 3584, yout[62]); AST(q3, 3840, yout[63]);
    // Fire-and-forget: no vmcnt wait after the stores; wave ends.
}

extern "C" void kernel_launch(void* const* d_in, const int* in_sizes, int n_in,
                              void* d_out, int out_size, void* d_ws, size_t ws_size,
                              hipStream_t stream) {
    const float* x   = (const float*)d_in[0];   // [B, T, C] fp32
    const float* sos = (const float*)d_in[1];   // [S, 6] fp32
    float* out = (float*)d_out;                 // [B, T, C] fp32
    sos_kernel<<<NBLOCKS, BLOCK, 0, stream>>>(x, sos, out);
}